// Round 12
// baseline (108.108 us; speedup 1.0000x reference)
//
#include <hip/hip_runtime.h>
#include <cstdint>
#include <cstddef>

typedef __attribute__((ext_vector_type(8))) short bf16x8;
typedef __attribute__((ext_vector_type(4))) float f32x4;

__device__ __forceinline__ unsigned short f2bf(float f) {
  unsigned int u = __builtin_bit_cast(unsigned int, f);
  u += 0x7FFFu + ((u >> 16) & 1u);
  return (unsigned short)(u >> 16);
}
__device__ __forceinline__ float bf2f(unsigned short h) {
  unsigned int u = ((unsigned int)h) << 16;
  return __builtin_bit_cast(float, u);
}

__device__ __forceinline__ void gl_lds16(const unsigned short* g, unsigned short* l) {
  __builtin_amdgcn_global_load_lds(
      (const __attribute__((address_space(1))) unsigned int*)(uintptr_t)g,
      (__attribute__((address_space(3))) unsigned int*)(unsigned int)(uintptr_t)l,
      16, 0, 0);
}

// ============ k_prep: convert(x) + wtrans(Wqkv) + wtrans(Wproj) + rope table ============
__global__ void k_prep(const float* __restrict__ x,
                       const float* __restrict__ Wqkv,
                       const float* __restrict__ Wproj,
                       unsigned short* __restrict__ xb,
                       unsigned short* __restrict__ wqt,
                       unsigned short* __restrict__ wpt,
                       float2* __restrict__ cstab) {
  __shared__ float tile[32][33];
  const int bid = blockIdx.x, tid = threadIdx.x;
  if (bid < 4096) {
    int i = bid * 256 + tid;
    float4 v = reinterpret_cast<const float4*>(x)[i];
    uint2 o;
    o.x = (unsigned int)f2bf(v.x) | ((unsigned int)f2bf(v.y) << 16);
    o.y = (unsigned int)f2bf(v.z) | ((unsigned int)f2bf(v.w) << 16);
    reinterpret_cast<uint2*>(xb)[i] = o;
  } else if (bid < 8192) {
    const float* in; unsigned short* out; int rows, cols, bx, by;
    if (bid < 7168) { in = Wqkv; out = wqt; rows = 1024; cols = 3072; bx = (bid - 4096) % 96; by = (bid - 4096) / 96; }
    else            { in = Wproj; out = wpt; rows = 1024; cols = 1024; bx = (bid - 7168) % 32; by = (bid - 7168) / 32; }
    int c0 = bx * 32, r0 = by * 32;
    int tx = tid & 31, ty = tid >> 5;
#pragma unroll
    for (int j = 0; j < 4; j++)
      tile[ty + j * 8][tx] = in[(size_t)(r0 + ty + j * 8) * cols + c0 + tx];
    __syncthreads();
#pragma unroll
    for (int j = 0; j < 4; j++)
      out[(size_t)(c0 + ty + j * 8) * rows + r0 + tx] = f2bf(tile[tx][ty + j * 8]);
  } else {
    int i = (bid - 8192) * 256 + tid;   // t*32 + j
    int t = i >> 5, j = i & 31;
    float invf = __powf(10000.0f, -(float)j / 32.0f);
    float ang = (float)t * invf;
    cstab[i] = make_float2(cosf(ang), sinf(ang));
  }
}

// ============ qkv GEMM, counted-vmcnt 4-buffer ring (T3/T4) + fused RoPE epilogue ======
// 128x128 tile, BK=32, 4 waves. LDS ring: 4 bufs x (A 8KB + B 8KB) = 64KB, prefetch
// distance 3, ONE raw s_barrier + vmcnt(8) per K-tile (counted, never 0 mid-loop).
__global__ __launch_bounds__(256, 2) void k_gemm_qkv(const unsigned short* __restrict__ A,
                           const unsigned short* __restrict__ Bt,
                           const float2* __restrict__ cstab,
                           unsigned short* __restrict__ qh,
                           unsigned short* __restrict__ kh,
                           unsigned short* __restrict__ vt) {
  const int K = 1024;
  __shared__ unsigned short Ta[4][128 * 32];
  __shared__ unsigned short Tb[4][128 * 32];
  const int tid = threadIdx.x;
  const int bid0 = blockIdx.y * 24 + blockIdx.x;
  const int bid = (bid0 & 7) * 96 + (bid0 >> 3);
  const int m0 = (bid / 24) * 128, n0 = (bid % 24) * 128;
  const int w = tid >> 6, l = tid & 63;
  const int lr = l & 15, lg = l >> 4;
  const int wm = (w >> 1) * 64, wn = (w & 1) * 64;
  const int ssr = w * 32 + (l >> 2);
  const int ssc = (l & 3) * 8;
  f32x4 acc[4][4] = {};

  auto stage = [&](int t) {   // 4 gl_lds per wave per K-tile
    int buf = t & 3;
    unsigned short* ta0 = &Ta[buf][w * 1024];
    unsigned short* tb0 = &Tb[buf][w * 1024];
    int k0 = t * 32;
    gl_lds16(&A [(size_t)(m0 + ssr) * K + k0 + ssc],      ta0);
    gl_lds16(&A [(size_t)(m0 + ssr + 16) * K + k0 + ssc], ta0 + 512);
    gl_lds16(&Bt[(size_t)(n0 + ssr) * K + k0 + ssc],      tb0);
    gl_lds16(&Bt[(size_t)(n0 + ssr + 16) * K + k0 + ssc], tb0 + 512);
  };

  stage(0); stage(1); stage(2);
  asm volatile("s_waitcnt vmcnt(8)" ::: "memory");   // tile 0 landed; 1,2 in flight
  asm volatile("s_barrier" ::: "memory");

  for (int t = 0; t < 32; t++) {
    if (t < 29) stage(t + 3);   // buf (t+3)&3 held tile t-1, reads done pre-barrier
    const unsigned short* TA = &Ta[t & 3][0];
    const unsigned short* TB = &Tb[t & 3][0];
    bf16x8 af[4], bfr[4];
#pragma unroll
    for (int i = 0; i < 4; i++)
      af[i] = *(const bf16x8*)&TA[(wm + i * 16 + lr) * 32 + lg * 8];
#pragma unroll
    for (int j = 0; j < 4; j++)
      bfr[j] = *(const bf16x8*)&TB[(wn + j * 16 + lr) * 32 + lg * 8];
    __builtin_amdgcn_s_setprio(1);
#pragma unroll
    for (int i = 0; i < 4; i++)
#pragma unroll
      for (int j = 0; j < 4; j++)
        acc[i][j] = __builtin_amdgcn_mfma_f32_16x16x32_bf16(af[i], bfr[j], acc[i][j], 0, 0, 0);
    __builtin_amdgcn_s_setprio(0);
    if (t < 31) {               // ensure tile t+1 landed; keep t+2/t+3 in flight
      if (t < 29)       asm volatile("s_waitcnt vmcnt(8)" ::: "memory");
      else if (t == 29) asm volatile("s_waitcnt vmcnt(4)" ::: "memory");
      else              asm volatile("s_waitcnt vmcnt(0)" ::: "memory");
      asm volatile("s_barrier" ::: "memory");
    }
  }

  const int part = n0 >> 10;                 // 0=q, 1=k, 2=v (block-uniform)
  const int hbase = (n0 & 1023) + wn;        // multiple of 64
  if (part < 2) {
    unsigned short* dst = part ? kh : qh;
    const float scale = part ? 1.0f : 0.180336880111120420f;
#pragma unroll
    for (int i = 0; i < 4; i++) {
#pragma unroll
      for (int r = 0; r < 4; r++) {
        int gm = m0 + wm + i * 16 + lg * 4 + r;
        int t = gm & 2047, b = gm >> 11;
        float2 cs0 = cstab[t * 32 + lr];
        float2 cs1 = cstab[t * 32 + 16 + lr];
#pragma unroll
        for (int j = 0; j < 4; j++) {
          float val = acc[i][j][r];
          float par = acc[i][j ^ 2][r];
          float2 cs = (j & 1) ? cs1 : cs0;
          float out = (j < 2) ? (val * cs.x - par * cs.y)
                              : (val * cs.x + par * cs.y);
          int h = (hbase + j * 16) >> 6;
          int d = j * 16 + lr;
          int bh = b * 16 + h;
          dst[((size_t)(bh * 2048 + t)) * 64 + d] = f2bf(out * scale);
        }
      }
    }
  } else {
#pragma unroll
    for (int i = 0; i < 4; i++) {
      int tb = m0 + wm + i * 16 + lg * 4;
      int t0 = tb & 2047, b = tb >> 11;
#pragma unroll
      for (int j = 0; j < 4; j++) {
        int h = (hbase + j * 16) >> 6;
        int d = j * 16 + lr;
        int bh = b * 16 + h;
        unsigned short pv[4];
#pragma unroll
        for (int r = 0; r < 4; r++) pv[r] = f2bf(acc[i][j][r]);
        *(uint2*)&vt[((size_t)(bh * 64 + d)) * 2048 + t0] = *(uint2*)pv;
      }
    }
  }
}

// ============ proj GEMM, counted-vmcnt 4-buffer ring, 64x128 tiles, 3 blocks/CU ========
__global__ __launch_bounds__(256, 3) void k_gemm_proj(const unsigned short* __restrict__ A,
                            const unsigned short* __restrict__ Bt,
                            float* __restrict__ C) {
  const int K = 1024;
  __shared__ unsigned short Ta[4][64 * 32];    // 16KB
  __shared__ unsigned short Tb[4][128 * 32];   // 32KB
  const int tid = threadIdx.x;
  const int bid0 = blockIdx.x;
  const int bid = (bid0 & 7) * 64 + (bid0 >> 3);
  const int n0 = (bid & 7) * 128;
  const int m0 = (bid >> 3) * 64;
  const int w = tid >> 6, l = tid & 63;
  const int lr = l & 15, lg = l >> 4;
  const int wn = w * 32;
  const int sra = tid >> 2, sca = (tid & 3) * 8;
  f32x4 acc[4][2] = {};

  auto stage = [&](int t) {   // 3 gl_lds per wave per K-tile
    int buf = t & 3;
    int k0 = t * 32;
    gl_lds16(&A[(size_t)(m0 + sra) * K + k0 + sca],        &Ta[buf][0] + tid * 8);
    gl_lds16(&Bt[(size_t)(n0 + sra) * K + k0 + sca],       &Tb[buf][0] + tid * 8);
    gl_lds16(&Bt[(size_t)(n0 + 64 + sra) * K + k0 + sca],  &Tb[buf][0] + (tid + 256) * 8);
  };

  stage(0); stage(1); stage(2);
  asm volatile("s_waitcnt vmcnt(6)" ::: "memory");
  asm volatile("s_barrier" ::: "memory");

  for (int t = 0; t < 32; t++) {
    if (t < 29) stage(t + 3);
    const unsigned short* TA = &Ta[t & 3][0];
    const unsigned short* TB = &Tb[t & 3][0];
    bf16x8 af[4], bfr[2];
#pragma unroll
    for (int i = 0; i < 4; i++)
      af[i] = *(const bf16x8*)&TA[(i * 16 + lr) * 32 + lg * 8];
#pragma unroll
    for (int j = 0; j < 2; j++)
      bfr[j] = *(const bf16x8*)&TB[(wn + j * 16 + lr) * 32 + lg * 8];
    __builtin_amdgcn_s_setprio(1);
#pragma unroll
    for (int i = 0; i < 4; i++)
#pragma unroll
      for (int j = 0; j < 2; j++)
        acc[i][j] = __builtin_amdgcn_mfma_f32_16x16x32_bf16(af[i], bfr[j], acc[i][j], 0, 0, 0);
    __builtin_amdgcn_s_setprio(0);
    if (t < 31) {
      if (t < 29)       asm volatile("s_waitcnt vmcnt(6)" ::: "memory");
      else if (t == 29) asm volatile("s_waitcnt vmcnt(3)" ::: "memory");
      else              asm volatile("s_waitcnt vmcnt(0)" ::: "memory");
      asm volatile("s_barrier" ::: "memory");
    }
  }
#pragma unroll
  for (int i = 0; i < 4; i++)
#pragma unroll
    for (int j = 0; j < 2; j++)
#pragma unroll
      for (int r = 0; r < 4; r++)
        C[(size_t)(m0 + i * 16 + lg * 4 + r) * 1024 + n0 + wn + j * 16 + lr] = acc[i][j][r];
}

// ---------------- causal flash attention: R3 step, 1 tile/block, 4 blocks/CU ----------
// (R11 version, 43.0 us measured — unchanged)
__global__ __launch_bounds__(256, 4) void k_attn(const unsigned short* __restrict__ qh,
                       const unsigned short* __restrict__ kh,
                       const unsigned short* __restrict__ vt,
                       unsigned short* __restrict__ att) {
  __shared__ unsigned short Kl[64 * 64];   // [k][d]
  __shared__ unsigned short Vl[64 * 64];   // [d][k]  (V^T)
  __shared__ unsigned short Pl[4][16 * 64];// per-wave [q][k]
  const int bid = blockIdx.x;
  const int xcd = bid & 7, u = bid >> 3;
  const int hl = u >> 5, v = u & 31;
  int qt;
  if      (hl == 0) qt = v;
  else if (hl == 1) qt = 31 - v;
  else if (hl == 2) qt = (v + 16) & 31;
  else              qt = (47 - v) & 31;
  const int bh = xcd * 4 + hl;
  const int b = bh >> 4, h = bh & 15;
  const int tid = threadIdx.x;
  const int w = tid >> 6, l = tid & 63;
  const int lr = l & 15, lg = l >> 4;
  const unsigned short* qbase = qh + (size_t)bh * 2048 * 64;
  const unsigned short* kbase = kh + (size_t)bh * 2048 * 64;
  const unsigned short* vbase = vt + (size_t)bh * 64 * 2048;
  char* KB = (char*)Kl;
  char* VB = (char*)Vl;
  char* PB = (char*)&Pl[w][0];
  const int swz = (lr & 7) << 4;
  const int sr = tid >> 2, sc = (tid & 3) * 16;
  const int sb0 = (sr * 128 + sc * 2) ^ ((sr & 7) << 4);
  const int sb1 = (sr * 128 + sc * 2 + 16) ^ ((sr & 7) << 4);

  const int q0 = qt * 64;
  const int qrow = q0 + w * 16 + lr;
  bf16x8 qa = *(const bf16x8*)&qbase[(size_t)qrow * 64 + lg * 8];
  bf16x8 qb = *(const bf16x8*)&qbase[(size_t)qrow * 64 + 32 + lg * 8];

  float mr = -3.0e38f, ls = 0.0f;
  f32x4 of[4] = {};
  uint4 ka0, ka1, va0, va1;   // in-flight K/V tile (T14)

  auto issue = [&](int kv0) {
    const unsigned short* ksrc = &kbase[(size_t)(kv0 + sr) * 64 + sc];
    const unsigned short* vsrc = &vbase[(size_t)sr * 2048 + kv0 + sc];
    ka0 = *(const uint4*)ksrc; ka1 = *(const uint4*)(ksrc + 8);
    va0 = *(const uint4*)vsrc; va1 = *(const uint4*)(vsrc + 8);
  };

  issue(0);
  for (int kb = 0; kb <= qt; kb++) {
    const int kv0 = kb * 64;
    __syncthreads();
    *(uint4*)(KB + sb0) = ka0;  *(uint4*)(KB + sb1) = ka1;
    *(uint4*)(VB + sb0) = va0;  *(uint4*)(VB + sb1) = va1;
    __syncthreads();
    if (kb < qt) issue((kb + 1) * 64);   // T14

    f32x4 s[4] = {};
    __builtin_amdgcn_s_setprio(1);
#pragma unroll
    for (int kq = 0; kq < 4; kq++) {
      bf16x8 kf0 = *(const bf16x8*)(KB + (((kq * 16 + lr) * 128 + lg * 16) ^ swz));
      bf16x8 kf1 = *(const bf16x8*)(KB + (((kq * 16 + lr) * 128 + 64 + lg * 16) ^ swz));
      s[kq] = __builtin_amdgcn_mfma_f32_16x16x32_bf16(kf0, qa, s[kq], 0, 0, 0);
      s[kq] = __builtin_amdgcn_mfma_f32_16x16x32_bf16(kf1, qb, s[kq], 0, 0, 0);
    }
    __builtin_amdgcn_s_setprio(0);
    if (kb == qt) {
#pragma unroll
      for (int kq = 0; kq < 4; kq++)
#pragma unroll
        for (int r = 0; r < 4; r++)
          if (kv0 + kq * 16 + lg * 4 + r > qrow) s[kq][r] = -3.0e38f;
    }
    float pm = s[0][0];
#pragma unroll
    for (int kq = 0; kq < 4; kq++)
#pragma unroll
      for (int r = 0; r < 4; r++) pm = fmaxf(pm, s[kq][r]);
    pm = fmaxf(pm, __shfl_xor(pm, 16));
    pm = fmaxf(pm, __shfl_xor(pm, 32));
    float mnew = fmaxf(mr, pm);
    float alpha = __builtin_amdgcn_exp2f(mr - mnew);
    mr = mnew;
    float psum = 0.0f;
#pragma unroll
    for (int kq = 0; kq < 4; kq++)
#pragma unroll
      for (int r = 0; r < 4; r++) {
        float p = __builtin_amdgcn_exp2f(s[kq][r] - mnew);
        s[kq][r] = p;
        psum += p;
      }
    psum += __shfl_xor(psum, 16);
    psum += __shfl_xor(psum, 32);
    ls = ls * alpha + psum;
#pragma unroll
    for (int n = 0; n < 4; n++) {
      of[n][0] *= alpha; of[n][1] *= alpha; of[n][2] *= alpha; of[n][3] *= alpha;
    }
#pragma unroll
    for (int kq = 0; kq < 4; kq++) {
      uint2 pk;
      asm("v_cvt_pk_bf16_f32 %0, %1, %2" : "=v"(pk.x) : "v"(s[kq][0]), "v"(s[kq][1]));
      asm("v_cvt_pk_bf16_f32 %0, %1, %2" : "=v"(pk.y) : "v"(s[kq][2]), "v"(s[kq][3]));
      *(uint2*)(PB + ((lr * 128 + (kq * 16 + lg * 4) * 2) ^ swz)) = pk;
    }
    bf16x8 pb0 = *(const bf16x8*)(PB + ((lr * 128 + lg * 16) ^ swz));
    bf16x8 pb1 = *(const bf16x8*)(PB + ((lr * 128 + 64 + lg * 16) ^ swz));
    __builtin_amdgcn_s_setprio(1);
#pragma unroll
    for (int n = 0; n < 4; n++) {
      bf16x8 vf0 = *(const bf16x8*)(VB + (((n * 16 + lr) * 128 + lg * 16) ^ swz));
      bf16x8 vf1 = *(const bf16x8*)(VB + (((n * 16 + lr) * 128 + 64 + lg * 16) ^ swz));
      of[n] = __builtin_amdgcn_mfma_f32_16x16x32_bf16(vf0, pb0, of[n], 0, 0, 0);
      of[n] = __builtin_amdgcn_mfma_f32_16x16x32_bf16(vf1, pb1, of[n], 0, 0, 0);
    }
    __builtin_amdgcn_s_setprio(0);
  }

  float inv = 1.0f / ls;
#pragma unroll
  for (int n = 0; n < 4; n++) {
    uint2 pk;
    float o0 = of[n][0] * inv, o1 = of[n][1] * inv, o2 = of[n][2] * inv, o3 = of[n][3] * inv;
    asm("v_cvt_pk_bf16_f32 %0, %1, %2" : "=v"(pk.x) : "v"(o0), "v"(o1));
    asm("v_cvt_pk_bf16_f32 %0, %1, %2" : "=v"(pk.y) : "v"(o2), "v"(o3));
    *(uint2*)(PB + ((lr * 128 + (n * 16 + lg * 4) * 2) ^ swz)) = pk;
  }
  {
    int r2 = l >> 2, c2 = (l & 3) * 16;
    int bo0 = (r2 * 128 + c2 * 2) ^ ((r2 & 7) << 4);
    int bo1 = (r2 * 128 + c2 * 2 + 16) ^ ((r2 & 7) << 4);
    uint4 o0 = *(const uint4*)(PB + bo0);
    uint4 o1 = *(const uint4*)(PB + bo1);
    unsigned short* orow = att + (size_t)(b * 2048 + q0 + w * 16 + r2) * 1024 + h * 64 + c2;
    *(uint4*)orow = o0;
    *(uint4*)(orow + 8) = o1;
  }
}

extern "C" void kernel_launch(void* const* d_in, const int* in_sizes, int n_in,
                              void* d_out, int out_size, void* d_ws, size_t ws_size,
                              hipStream_t stream) {
  const float* x     = (const float*)d_in[0];
  const float* Wqkv  = (const float*)d_in[1];
  const float* Wproj = (const float*)d_in[2];
  float* out = (float*)d_out;

  char* ws = (char*)d_ws;
  size_t off = 0;
  auto alloc = [&](size_t bytes) { void* p = ws + off; off += (bytes + 255) & ~(size_t)255; return p; };
  unsigned short* xb   = (unsigned short*)alloc((size_t)4096 * 1024 * 2);
  unsigned short* wqt  = (unsigned short*)alloc((size_t)3072 * 1024 * 2);
  unsigned short* wpt  = (unsigned short*)alloc((size_t)1024 * 1024 * 2);
  unsigned short* qh   = (unsigned short*)alloc((size_t)32 * 2048 * 64 * 2);
  unsigned short* kh   = (unsigned short*)alloc((size_t)32 * 2048 * 64 * 2);
  unsigned short* vt   = (unsigned short*)alloc((size_t)32 * 64 * 2048 * 2);
  unsigned short* att  = (unsigned short*)alloc((size_t)4096 * 1024 * 2);
  float2* cstab = (float2*)alloc((size_t)2048 * 32 * 8);

  k_prep<<<8448, 256, 0, stream>>>(x, Wqkv, Wproj, xb, wqt, wpt, cstab);
  k_gemm_qkv<<<dim3(24, 32), 256, 0, stream>>>(xb, wqt, cstab, qh, kh, vt);
  k_attn<<<1024, 256, 0, stream>>>(qh, kh, vt, att);
  k_gemm_proj<<<512, 256, 0, stream>>>(att, wpt, out);
}

// Round 13
// 103.379 us; speedup vs baseline: 1.0457x; 1.0457x over previous
//
#include <hip/hip_runtime.h>
#include <cstdint>
#include <cstddef>

typedef __attribute__((ext_vector_type(8))) short bf16x8;
typedef __attribute__((ext_vector_type(4))) float f32x4;

__device__ __forceinline__ unsigned short f2bf(float f) {
  unsigned int u = __builtin_bit_cast(unsigned int, f);
  u += 0x7FFFu + ((u >> 16) & 1u);
  return (unsigned short)(u >> 16);
}
__device__ __forceinline__ float bf2f(unsigned short h) {
  unsigned int u = ((unsigned int)h) << 16;
  return __builtin_bit_cast(float, u);
}

__device__ __forceinline__ void gl_lds16(const unsigned short* g, unsigned short* l) {
  __builtin_amdgcn_global_load_lds(
      (const __attribute__((address_space(1))) unsigned int*)(uintptr_t)g,
      (__attribute__((address_space(3))) unsigned int*)(unsigned int)(uintptr_t)l,
      16, 0, 0);
}

// ============ k_prep: convert(x) + wtrans(Wqkv) + wtrans(Wproj) + rope table ============
__global__ void k_prep(const float* __restrict__ x,
                       const float* __restrict__ Wqkv,
                       const float* __restrict__ Wproj,
                       unsigned short* __restrict__ xb,
                       unsigned short* __restrict__ wqt,
                       unsigned short* __restrict__ wpt,
                       float2* __restrict__ cstab) {
  __shared__ float tile[32][33];
  const int bid = blockIdx.x, tid = threadIdx.x;
  if (bid < 4096) {
    int i = bid * 256 + tid;
    float4 v = reinterpret_cast<const float4*>(x)[i];
    uint2 o;
    o.x = (unsigned int)f2bf(v.x) | ((unsigned int)f2bf(v.y) << 16);
    o.y = (unsigned int)f2bf(v.z) | ((unsigned int)f2bf(v.w) << 16);
    reinterpret_cast<uint2*>(xb)[i] = o;
  } else if (bid < 8192) {
    const float* in; unsigned short* out; int rows, cols, bx, by;
    if (bid < 7168) { in = Wqkv; out = wqt; rows = 1024; cols = 3072; bx = (bid - 4096) % 96; by = (bid - 4096) / 96; }
    else            { in = Wproj; out = wpt; rows = 1024; cols = 1024; bx = (bid - 7168) % 32; by = (bid - 7168) / 32; }
    int c0 = bx * 32, r0 = by * 32;
    int tx = tid & 31, ty = tid >> 5;
#pragma unroll
    for (int j = 0; j < 4; j++)
      tile[ty + j * 8][tx] = in[(size_t)(r0 + ty + j * 8) * cols + c0 + tx];
    __syncthreads();
#pragma unroll
    for (int j = 0; j < 4; j++)
      out[(size_t)(c0 + ty + j * 8) * rows + r0 + tx] = f2bf(tile[tx][ty + j * 8]);
  } else {
    int i = (bid - 8192) * 256 + tid;   // t*32 + j
    int t = i >> 5, j = i & 31;
    float invf = __powf(10000.0f, -(float)j / 32.0f);
    float ang = (float)t * invf;
    cstab[i] = make_float2(cosf(ang), sinf(ang));
  }
}

// ============ qkv GEMM: two BK=32 tiles per barrier pair (32KB LDS, 5 blocks/CU) ======
// 128x128 tile, 4 waves, m97 staging per sub-tile (64B rows, conflict-free).
// Fused RoPE/head-split/V-transpose epilogue. T1 XCD swizzle.
__global__ void k_gemm_qkv(const unsigned short* __restrict__ A,
                           const unsigned short* __restrict__ Bt,
                           const float2* __restrict__ cstab,
                           unsigned short* __restrict__ qh,
                           unsigned short* __restrict__ kh,
                           unsigned short* __restrict__ vt) {
  const int K = 1024;
  __shared__ unsigned short Ta[2][128 * 32];
  __shared__ unsigned short Tb[2][128 * 32];
  const int tid = threadIdx.x;
  const int bid0 = blockIdx.y * 24 + blockIdx.x;
  const int bid = (bid0 & 7) * 96 + (bid0 >> 3);
  const int m0 = (bid / 24) * 128, n0 = (bid % 24) * 128;
  const int w = tid >> 6, l = tid & 63;
  const int lr = l & 15, lg = l >> 4;
  const int wm = (w >> 1) * 64, wn = (w & 1) * 64;
  const int ssr = w * 32 + (l >> 2);
  const int ssc = (l & 3) * 8;
  f32x4 acc[4][4] = {};
  for (int t = 0; t < 16; t++) {
    const int k0 = t * 64;
    __syncthreads();
#pragma unroll
    for (int hf = 0; hf < 2; hf++) {
      unsigned short* ta0 = &Ta[hf][w * 1024];
      unsigned short* tb0 = &Tb[hf][w * 1024];
      int kk = k0 + hf * 32;
      gl_lds16(&A [(size_t)(m0 + ssr) * K + kk + ssc],      ta0);
      gl_lds16(&A [(size_t)(m0 + ssr + 16) * K + kk + ssc], ta0 + 512);
      gl_lds16(&Bt[(size_t)(n0 + ssr) * K + kk + ssc],      tb0);
      gl_lds16(&Bt[(size_t)(n0 + ssr + 16) * K + kk + ssc], tb0 + 512);
    }
    __syncthreads();
#pragma unroll
    for (int hf = 0; hf < 2; hf++) {
      bf16x8 af[4], bfr[4];
#pragma unroll
      for (int i = 0; i < 4; i++)
        af[i] = *(const bf16x8*)&Ta[hf][(wm + i * 16 + lr) * 32 + lg * 8];
#pragma unroll
      for (int j = 0; j < 4; j++)
        bfr[j] = *(const bf16x8*)&Tb[hf][(wn + j * 16 + lr) * 32 + lg * 8];
#pragma unroll
      for (int i = 0; i < 4; i++)
#pragma unroll
        for (int j = 0; j < 4; j++)
          acc[i][j] = __builtin_amdgcn_mfma_f32_16x16x32_bf16(af[i], bfr[j], acc[i][j], 0, 0, 0);
    }
  }
  const int part = n0 >> 10;                 // 0=q, 1=k, 2=v (block-uniform)
  const int hbase = (n0 & 1023) + wn;        // multiple of 64
  if (part < 2) {
    unsigned short* dst = part ? kh : qh;
    const float scale = part ? 1.0f : 0.180336880111120420f;
#pragma unroll
    for (int i = 0; i < 4; i++) {
#pragma unroll
      for (int r = 0; r < 4; r++) {
        int gm = m0 + wm + i * 16 + lg * 4 + r;
        int t = gm & 2047, b = gm >> 11;
        float2 cs0 = cstab[t * 32 + lr];
        float2 cs1 = cstab[t * 32 + 16 + lr];
#pragma unroll
        for (int j = 0; j < 4; j++) {
          float val = acc[i][j][r];
          float par = acc[i][j ^ 2][r];
          float2 cs = (j & 1) ? cs1 : cs0;
          float out = (j < 2) ? (val * cs.x - par * cs.y)
                              : (val * cs.x + par * cs.y);
          int h = (hbase + j * 16) >> 6;
          int d = j * 16 + lr;
          int bh = b * 16 + h;
          dst[((size_t)(bh * 2048 + t)) * 64 + d] = f2bf(out * scale);
        }
      }
    }
  } else {
#pragma unroll
    for (int i = 0; i < 4; i++) {
      int tb = m0 + wm + i * 16 + lg * 4;
      int t0 = tb & 2047, b = tb >> 11;
#pragma unroll
      for (int j = 0; j < 4; j++) {
        int h = (hbase + j * 16) >> 6;
        int d = j * 16 + lr;
        int bh = b * 16 + h;
        unsigned short pv[4];
#pragma unroll
        for (int r = 0; r < 4; r++) pv[r] = f2bf(acc[i][j][r]);
        *(uint2*)&vt[((size_t)(bh * 64 + d)) * 2048 + t0] = *(uint2*)pv;
      }
    }
  }
}

// ============ proj GEMM: two BK=32 tiles per barrier pair (24KB LDS, 6 blocks/CU) ======
__global__ void k_gemm_proj(const unsigned short* __restrict__ A,
                            const unsigned short* __restrict__ Bt,
                            float* __restrict__ C) {
  const int K = 1024;
  __shared__ unsigned short Ta[2][64 * 32];
  __shared__ unsigned short Tb[2][128 * 32];
  const int tid = threadIdx.x;
  const int bid0 = blockIdx.x;
  const int bid = (bid0 & 7) * 64 + (bid0 >> 3);
  const int n0 = (bid & 7) * 128;
  const int m0 = (bid >> 3) * 64;
  const int w = tid >> 6, l = tid & 63;
  const int lr = l & 15, lg = l >> 4;
  const int wn = w * 32;
  const int sra = tid >> 2, sca = (tid & 3) * 8;
  f32x4 acc[4][2] = {};
  for (int t = 0; t < 16; t++) {
    const int k0 = t * 64;
    __syncthreads();
#pragma unroll
    for (int hf = 0; hf < 2; hf++) {
      int kk = k0 + hf * 32;
      gl_lds16(&A[(size_t)(m0 + sra) * K + kk + sca],        &Ta[hf][0] + tid * 8);
      gl_lds16(&Bt[(size_t)(n0 + sra) * K + kk + sca],       &Tb[hf][0] + tid * 8);
      gl_lds16(&Bt[(size_t)(n0 + 64 + sra) * K + kk + sca],  &Tb[hf][0] + (tid + 256) * 8);
    }
    __syncthreads();
#pragma unroll
    for (int hf = 0; hf < 2; hf++) {
      bf16x8 af[4], bfr[2];
#pragma unroll
      for (int i = 0; i < 4; i++)
        af[i] = *(const bf16x8*)&Ta[hf][(i * 16 + lr) * 32 + lg * 8];
#pragma unroll
      for (int j = 0; j < 2; j++)
        bfr[j] = *(const bf16x8*)&Tb[hf][(wn + j * 16 + lr) * 32 + lg * 8];
#pragma unroll
      for (int i = 0; i < 4; i++)
#pragma unroll
        for (int j = 0; j < 2; j++)
          acc[i][j] = __builtin_amdgcn_mfma_f32_16x16x32_bf16(af[i], bfr[j], acc[i][j], 0, 0, 0);
    }
  }
#pragma unroll
  for (int i = 0; i < 4; i++)
#pragma unroll
    for (int j = 0; j < 2; j++)
#pragma unroll
      for (int r = 0; r < 4; r++)
        C[(size_t)(m0 + i * 16 + lg * 4 + r) * 1024 + n0 + wn + j * 16 + lr] = acc[i][j][r];
}

// ---------------- causal flash attention: R11 version (43.0 us measured) --------------
__global__ __launch_bounds__(256, 4) void k_attn(const unsigned short* __restrict__ qh,
                       const unsigned short* __restrict__ kh,
                       const unsigned short* __restrict__ vt,
                       unsigned short* __restrict__ att) {
  __shared__ unsigned short Kl[64 * 64];   // [k][d]
  __shared__ unsigned short Vl[64 * 64];   // [d][k]  (V^T)
  __shared__ unsigned short Pl[4][16 * 64];// per-wave [q][k]
  const int bid = blockIdx.x;
  const int xcd = bid & 7, u = bid >> 3;
  const int hl = u >> 5, v = u & 31;
  int qt;
  if      (hl == 0) qt = v;
  else if (hl == 1) qt = 31 - v;
  else if (hl == 2) qt = (v + 16) & 31;
  else              qt = (47 - v) & 31;
  const int bh = xcd * 4 + hl;
  const int b = bh >> 4, h = bh & 15;
  const int tid = threadIdx.x;
  const int w = tid >> 6, l = tid & 63;
  const int lr = l & 15, lg = l >> 4;
  const unsigned short* qbase = qh + (size_t)bh * 2048 * 64;
  const unsigned short* kbase = kh + (size_t)bh * 2048 * 64;
  const unsigned short* vbase = vt + (size_t)bh * 64 * 2048;
  char* KB = (char*)Kl;
  char* VB = (char*)Vl;
  char* PB = (char*)&Pl[w][0];
  const int swz = (lr & 7) << 4;
  const int sr = tid >> 2, sc = (tid & 3) * 16;
  const int sb0 = (sr * 128 + sc * 2) ^ ((sr & 7) << 4);
  const int sb1 = (sr * 128 + sc * 2 + 16) ^ ((sr & 7) << 4);

  const int q0 = qt * 64;
  const int qrow = q0 + w * 16 + lr;
  bf16x8 qa = *(const bf16x8*)&qbase[(size_t)qrow * 64 + lg * 8];
  bf16x8 qb = *(const bf16x8*)&qbase[(size_t)qrow * 64 + 32 + lg * 8];

  float mr = -3.0e38f, ls = 0.0f;
  f32x4 of[4] = {};
  uint4 ka0, ka1, va0, va1;   // in-flight K/V tile (T14)

  auto issue = [&](int kv0) {
    const unsigned short* ksrc = &kbase[(size_t)(kv0 + sr) * 64 + sc];
    const unsigned short* vsrc = &vbase[(size_t)sr * 2048 + kv0 + sc];
    ka0 = *(const uint4*)ksrc; ka1 = *(const uint4*)(ksrc + 8);
    va0 = *(const uint4*)vsrc; va1 = *(const uint4*)(vsrc + 8);
  };

  issue(0);
  for (int kb = 0; kb <= qt; kb++) {
    const int kv0 = kb * 64;
    __syncthreads();
    *(uint4*)(KB + sb0) = ka0;  *(uint4*)(KB + sb1) = ka1;
    *(uint4*)(VB + sb0) = va0;  *(uint4*)(VB + sb1) = va1;
    __syncthreads();
    if (kb < qt) issue((kb + 1) * 64);   // T14

    f32x4 s[4] = {};
    __builtin_amdgcn_s_setprio(1);
#pragma unroll
    for (int kq = 0; kq < 4; kq++) {
      bf16x8 kf0 = *(const bf16x8*)(KB + (((kq * 16 + lr) * 128 + lg * 16) ^ swz));
      bf16x8 kf1 = *(const bf16x8*)(KB + (((kq * 16 + lr) * 128 + 64 + lg * 16) ^ swz));
      s[kq] = __builtin_amdgcn_mfma_f32_16x16x32_bf16(kf0, qa, s[kq], 0, 0, 0);
      s[kq] = __builtin_amdgcn_mfma_f32_16x16x32_bf16(kf1, qb, s[kq], 0, 0, 0);
    }
    __builtin_amdgcn_s_setprio(0);
    if (kb == qt) {
#pragma unroll
      for (int kq = 0; kq < 4; kq++)
#pragma unroll
        for (int r = 0; r < 4; r++)
          if (kv0 + kq * 16 + lg * 4 + r > qrow) s[kq][r] = -3.0e38f;
    }
    float pm = s[0][0];
#pragma unroll
    for (int kq = 0; kq < 4; kq++)
#pragma unroll
      for (int r = 0; r < 4; r++) pm = fmaxf(pm, s[kq][r]);
    pm = fmaxf(pm, __shfl_xor(pm, 16));
    pm = fmaxf(pm, __shfl_xor(pm, 32));
    float mnew = fmaxf(mr, pm);
    float alpha = __builtin_amdgcn_exp2f(mr - mnew);
    mr = mnew;
    float psum = 0.0f;
#pragma unroll
    for (int kq = 0; kq < 4; kq++)
#pragma unroll
      for (int r = 0; r < 4; r++) {
        float p = __builtin_amdgcn_exp2f(s[kq][r] - mnew);
        s[kq][r] = p;
        psum += p;
      }
    psum += __shfl_xor(psum, 16);
    psum += __shfl_xor(psum, 32);
    ls = ls * alpha + psum;
#pragma unroll
    for (int n = 0; n < 4; n++) {
      of[n][0] *= alpha; of[n][1] *= alpha; of[n][2] *= alpha; of[n][3] *= alpha;
    }
#pragma unroll
    for (int kq = 0; kq < 4; kq++) {
      uint2 pk;
      asm("v_cvt_pk_bf16_f32 %0, %1, %2" : "=v"(pk.x) : "v"(s[kq][0]), "v"(s[kq][1]));
      asm("v_cvt_pk_bf16_f32 %0, %1, %2" : "=v"(pk.y) : "v"(s[kq][2]), "v"(s[kq][3]));
      *(uint2*)(PB + ((lr * 128 + (kq * 16 + lg * 4) * 2) ^ swz)) = pk;
    }
    bf16x8 pb0 = *(const bf16x8*)(PB + ((lr * 128 + lg * 16) ^ swz));
    bf16x8 pb1 = *(const bf16x8*)(PB + ((lr * 128 + 64 + lg * 16) ^ swz));
    __builtin_amdgcn_s_setprio(1);
#pragma unroll
    for (int n = 0; n < 4; n++) {
      bf16x8 vf0 = *(const bf16x8*)(VB + (((n * 16 + lr) * 128 + lg * 16) ^ swz));
      bf16x8 vf1 = *(const bf16x8*)(VB + (((n * 16 + lr) * 128 + 64 + lg * 16) ^ swz));
      of[n] = __builtin_amdgcn_mfma_f32_16x16x32_bf16(vf0, pb0, of[n], 0, 0, 0);
      of[n] = __builtin_amdgcn_mfma_f32_16x16x32_bf16(vf1, pb1, of[n], 0, 0, 0);
    }
    __builtin_amdgcn_s_setprio(0);
  }

  float inv = 1.0f / ls;
#pragma unroll
  for (int n = 0; n < 4; n++) {
    uint2 pk;
    float o0 = of[n][0] * inv, o1 = of[n][1] * inv, o2 = of[n][2] * inv, o3 = of[n][3] * inv;
    asm("v_cvt_pk_bf16_f32 %0, %1, %2" : "=v"(pk.x) : "v"(o0), "v"(o1));
    asm("v_cvt_pk_bf16_f32 %0, %1, %2" : "=v"(pk.y) : "v"(o2), "v"(o3));
    *(uint2*)(PB + ((lr * 128 + (n * 16 + lg * 4) * 2) ^ swz)) = pk;
  }
  {
    int r2 = l >> 2, c2 = (l & 3) * 16;
    int bo0 = (r2 * 128 + c2 * 2) ^ ((r2 & 7) << 4);
    int bo1 = (r2 * 128 + c2 * 2 + 16) ^ ((r2 & 7) << 4);
    uint4 o0 = *(const uint4*)(PB + bo0);
    uint4 o1 = *(const uint4*)(PB + bo1);
    unsigned short* orow = att + (size_t)(b * 2048 + q0 + w * 16 + r2) * 1024 + h * 64 + c2;
    *(uint4*)orow = o0;
    *(uint4*)(orow + 8) = o1;
  }
}

extern "C" void kernel_launch(void* const* d_in, const int* in_sizes, int n_in,
                              void* d_out, int out_size, void* d_ws, size_t ws_size,
                              hipStream_t stream) {
  const float* x     = (const float*)d_in[0];
  const float* Wqkv  = (const float*)d_in[1];
  const float* Wproj = (const float*)d_in[2];
  float* out = (float*)d_out;

  char* ws = (char*)d_ws;
  size_t off = 0;
  auto alloc = [&](size_t bytes) { void* p = ws + off; off += (bytes + 255) & ~(size_t)255; return p; };
  unsigned short* xb   = (unsigned short*)alloc((size_t)4096 * 1024 * 2);
  unsigned short* wqt  = (unsigned short*)alloc((size_t)3072 * 1024 * 2);
  unsigned short* wpt  = (unsigned short*)alloc((size_t)1024 * 1024 * 2);
  unsigned short* qh   = (unsigned short*)alloc((size_t)32 * 2048 * 64 * 2);
  unsigned short* kh   = (unsigned short*)alloc((size_t)32 * 2048 * 64 * 2);
  unsigned short* vt   = (unsigned short*)alloc((size_t)32 * 64 * 2048 * 2);
  unsigned short* att  = (unsigned short*)alloc((size_t)4096 * 1024 * 2);
  float2* cstab = (float2*)alloc((size_t)2048 * 32 * 8);

  k_prep<<<8448, 256, 0, stream>>>(x, Wqkv, Wproj, xb, wqt, wpt, cstab);
  k_gemm_qkv<<<dim3(24, 32), 256, 0, stream>>>(xb, wqt, cstab, qh, kh, vt);
  k_attn<<<1024, 256, 0, stream>>>(qh, kh, vt, att);
  k_gemm_proj<<<512, 256, 0, stream>>>(att, wpt, out);
}